// Round 1
// baseline (137.796 us; speedup 1.0000x reference)
//
#include <hip/hip_runtime.h>

// Problem constants (fixed by the reference setup)
#define Bc   2
#define Cc   256
#define Hc   80
#define Wc   160
#define Gc   4
#define Sc   9
#define GCc  64              // channels per group
#define HWc  (Hc * Wc)
#define H2c  (Hc / 2)        // 40 row-pair tiles
#define WTc  (Wc / 32)       // 5 col tiles of 32

// One wave (64 threads) per block.
// Block handles: one batch b, one group g, a 2-row x 32-col pixel tile.
// Lane -> pixel: r = lane>>5 (row within pair), col = lane&31.
// Per lane: precompute for each of the 9 window samples the two row base
// offsets (clamped in-plane) and 4 bilinear weights with zero-padding
// validity folded in, then loop over the 64 group channels doing 4 gathers
// + 5 FMAs per (c,s).
__global__ __launch_bounds__(64)
void aoc_corr_kernel(const float* __restrict__ left,
                     const float* __restrict__ right,
                     const float* __restrict__ flow,
                     const float* __restrict__ extra,
                     float* __restrict__ out)
{
    int bid = blockIdx.x;
    int wt = bid % WTc; bid /= WTc;
    int h2 = bid % H2c; bid /= H2c;
    int g  = bid % Gc;  bid /= Gc;
    int b  = bid;

    const int lane = threadIdx.x;
    const int r    = lane >> 5;
    const int col  = lane & 31;
    const int h    = h2 * 2 + r;
    const int w    = wt * 32 + col;
    const int pix  = h * Wc + w;

    // Base coords: absolute pixel + flow (channel 0 = x, channel 1 = y)
    const float* flowb = flow + (size_t)b * 2 * HWc;
    const float bx = (float)w + flowb[pix];
    const float by = (float)h + flowb[HWc + pix];

    int   offA[Sc], offB[Sc];
    float w00[Sc], w01[Sc], w10[Sc], w11[Sc];

    const float* exb = extra + (size_t)b * (2 * Sc) * HWc + pix;
#pragma unroll
    for (int s = 0; s < Sc; ++s) {
        const float ex = exb[(size_t)(2 * s) * HWc];
        const float ey = exb[(size_t)(2 * s + 1) * HWc];
        const float x = bx + (float)(s - 4) + ex;   // window offsets: x = s-4, y = 0
        const float y = by + ey;

        const float x0f = floorf(x);
        const float y0f = floorf(y);
        const float fx = x - x0f;
        const float fy = y - y0f;
        const int x0 = (int)x0f;
        const int y0 = (int)y0f;
        const int y1 = y0 + 1;

        // Column handling: we always read the pair (xb, xb+1) with
        // xb = clamp(x0, 0, W-2). Map the needed positions {x0, x0+1}
        // (with zero-padding validity) onto the two loaded components.
        const int xb = min(max(x0, 0), Wc - 2);
        const float cA = (x0 == xb) ? (1.0f - fx) : ((x0 == -1)     ? fx          : 0.0f);
        const float cB = (x0 == xb) ? fx          : ((x0 == Wc - 1) ? (1.0f - fx) : 0.0f);

        // Row validity folded into row weights; row index clamped for the load.
        const float r0 = (y0 >= 0 && y0 < Hc) ? (1.0f - fy) : 0.0f;
        const float r1 = (y1 >= 0 && y1 < Hc) ? fy          : 0.0f;
        const int yc0 = min(max(y0, 0), Hc - 1);
        const int yc1 = min(max(y1, 0), Hc - 1);

        w00[s] = cA * r0;  w01[s] = cB * r0;
        w10[s] = cA * r1;  w11[s] = cB * r1;
        offA[s] = yc0 * Wc + xb;     // element offset within one channel plane
        offB[s] = yc1 * Wc + xb;
    }

    const float* Rb = right + ((size_t)b * Cc + (size_t)g * GCc) * HWc;
    const float* Lb = left  + ((size_t)b * Cc + (size_t)g * GCc) * HWc + pix;

    float acc[Sc];
#pragma unroll
    for (int s = 0; s < Sc; ++s) acc[s] = 0.0f;

    for (int c = 0; c < GCc; ++c) {
        const float lv = Lb[(size_t)c * HWc];
        const float* Rc = Rb + (size_t)c * HWc;
#pragma unroll
        for (int s = 0; s < Sc; ++s) {
            const float vA0 = Rc[offA[s]];
            const float vA1 = Rc[offA[s] + 1];
            const float vB0 = Rc[offB[s]];
            const float vB1 = Rc[offB[s] + 1];
            acc[s] += lv * (w00[s] * vA0 + w01[s] * vA1 +
                            w10[s] * vB0 + w11[s] * vB1);
        }
    }

    // Output: (B, G*S, H, W), channel = g*S + s; mean over group channels.
    const float inv = 1.0f / (float)GCc;
    float* ob = out + ((size_t)b * Gc + g) * Sc * HWc + pix;
#pragma unroll
    for (int s = 0; s < Sc; ++s) ob[(size_t)s * HWc] = acc[s] * inv;
}

extern "C" void kernel_launch(void* const* d_in, const int* in_sizes, int n_in,
                              void* d_out, int out_size, void* d_ws, size_t ws_size,
                              hipStream_t stream) {
    const float* left  = (const float*)d_in[0];
    const float* right = (const float*)d_in[1];
    const float* flow  = (const float*)d_in[2];
    const float* extra = (const float*)d_in[3];
    float* out = (float*)d_out;

    const int nblocks = Bc * Gc * H2c * WTc;  // 2*4*40*5 = 1600
    aoc_corr_kernel<<<nblocks, 64, 0, stream>>>(left, right, flow, extra, out);
}

// Round 2
// 81.315 us; speedup vs baseline: 1.6946x; 1.6946x over previous
//
#include <hip/hip_runtime.h>

// Problem constants (fixed by the reference setup)
#define Bc   2
#define Cc   256
#define Hc   80
#define Wc   160
#define Gc   4
#define Sc   9
#define GCc  64              // channels per group
#define HWc  (Hc * Wc)
#define H2c  (Hc / 2)        // 40 row-pair tiles
#define WTc  (Wc / 32)       // 5 col tiles of 32

// LDS staging region budget (per block = 1 wave)
#define RROWS   24
#define RCOLS   64
#define RSTRIDE 65           // +1 pad: bank = (y + x) mod 32, rows decorrelate

typedef const __attribute__((address_space(1))) unsigned int* gas_ptr;
typedef __attribute__((address_space(3))) unsigned int* las_ptr;

// One wave per block: (b, g, 2-row x 32-col pixel tile).
// Phase A: per-lane coords/weights for 9 window samples; wave min/max of the
//          clamped sample footprint.
// Phase B (common case): per channel, stage the footprint rows into LDS with
//          coalesced global_load_lds, then 36 scattered reads hit LDS instead
//          of L1 (the round-1 kernel was L1 gather-transaction bound).
// Fallback (footprint too large, flow outliers): round-1 global gather path.
__global__ __launch_bounds__(64)
void aoc_corr_kernel(const float* __restrict__ left,
                     const float* __restrict__ right,
                     const float* __restrict__ flow,
                     const float* __restrict__ extra,
                     float* __restrict__ out)
{
    __shared__ float tile[RROWS * RSTRIDE];

    int bid = blockIdx.x;
    int wt = bid % WTc; bid /= WTc;
    int h2 = bid % H2c; bid /= H2c;
    int g  = bid % Gc;  bid /= Gc;
    int b  = bid;

    const int lane = threadIdx.x;
    const int r    = lane >> 5;
    const int col  = lane & 31;
    const int h    = h2 * 2 + r;
    const int w    = wt * 32 + col;
    const int pix  = h * Wc + w;

    const float* flowb = flow + (size_t)b * 2 * HWc;
    const float bx = (float)w + flowb[pix];
    const float by = (float)h + flowb[HWc + pix];

    int   xb9[Sc], y09[Sc], y19[Sc];
    float w00[Sc], w01[Sc], w10[Sc], w11[Sc];
    int minX = 1 << 30, maxX = -(1 << 30), minY = 1 << 30, maxY = -(1 << 30);

    const float* exb = extra + (size_t)b * (2 * Sc) * HWc + pix;
#pragma unroll
    for (int s = 0; s < Sc; ++s) {
        const float ex = exb[(size_t)(2 * s) * HWc];
        const float ey = exb[(size_t)(2 * s + 1) * HWc];
        const float x = bx + (float)(s - 4) + ex;   // window: x offset s-4, y 0
        const float y = by + ey;

        const float x0f = floorf(x);
        const float y0f = floorf(y);
        const float fx = x - x0f;
        const float fy = y - y0f;
        const int x0 = (int)x0f;
        const int y0 = (int)y0f;
        const int y1 = y0 + 1;

        const int xb = min(max(x0, 0), Wc - 2);
        const float cA = (x0 == xb) ? (1.0f - fx) : ((x0 == -1)     ? fx          : 0.0f);
        const float cB = (x0 == xb) ? fx          : ((x0 == Wc - 1) ? (1.0f - fx) : 0.0f);
        const float r0 = (y0 >= 0 && y0 < Hc) ? (1.0f - fy) : 0.0f;
        const float r1 = (y1 >= 0 && y1 < Hc) ? fy          : 0.0f;
        const int yc0 = min(max(y0, 0), Hc - 1);
        const int yc1 = min(max(y1, 0), Hc - 1);

        w00[s] = cA * r0;  w01[s] = cB * r0;
        w10[s] = cA * r1;  w11[s] = cB * r1;
        xb9[s] = xb;  y09[s] = yc0;  y19[s] = yc1;

        minX = min(minX, xb);
        maxX = max(maxX, xb);
        minY = min(minY, min(yc0, yc1));
        maxY = max(maxY, max(yc0, yc1));
    }

    // Wave-wide min/max of the (clamped) footprint
#pragma unroll
    for (int k = 1; k < 64; k <<= 1) {
        minX = min(minX, __shfl_xor(minX, k));
        maxX = max(maxX, __shfl_xor(maxX, k));
        minY = min(minY, __shfl_xor(minY, k));
        maxY = max(maxY, __shfl_xor(maxY, k));
    }
    const int nRows = maxY - minY + 1;          // covers yc0..yc1 for all lanes
    const int nCols = maxX + 2 - minX;          // covers xb..xb+1 for all lanes

    const float* Rb = right + ((size_t)b * Cc + (size_t)g * GCc) * HWc;
    const float* Lb = left  + ((size_t)b * Cc + (size_t)g * GCc) * HWc + pix;

    float acc[Sc];
#pragma unroll
    for (int s = 0; s < Sc; ++s) acc[s] = 0.0f;

    if (nRows <= RROWS && nCols <= RCOLS) {
        // LDS-relative word offsets per sample (all within staged region)
        int relA[Sc], relB[Sc];
#pragma unroll
        for (int s = 0; s < Sc; ++s) {
            relA[s] = (y09[s] - minY) * RSTRIDE + (xb9[s] - minX);
            relB[s] = (y19[s] - minY) * RSTRIDE + (xb9[s] - minX);
        }
        // Lane -> staged column (clamped in-plane; clamped dups are never read)
        const int laneCol = min(lane, (Wc - 1) - minX);
        const float* Rrow0 = Rb + minY * Wc + minX;

        for (int c = 0; c < GCc; ++c) {
            const float lv = Lb[(size_t)c * HWc];
            const float* Rc = Rrow0 + (size_t)c * HWc;

            // All prior LDS reads retired before overwriting the buffer;
            // memory clobber also stops the compiler hoisting the stores up.
            asm volatile("s_waitcnt lgkmcnt(0)" ::: "memory");
            for (int rr = 0; rr < nRows; ++rr) {
                __builtin_amdgcn_global_load_lds(
                    (gas_ptr)(Rc + rr * Wc + laneCol),
                    (las_ptr)&tile[rr * RSTRIDE], 4, 0, 0);
            }
            asm volatile("s_waitcnt vmcnt(0)" ::: "memory");

#pragma unroll
            for (int s = 0; s < Sc; ++s) {
                const float vA0 = tile[relA[s]];
                const float vA1 = tile[relA[s] + 1];
                const float vB0 = tile[relB[s]];
                const float vB1 = tile[relB[s] + 1];
                acc[s] += lv * (w00[s] * vA0 + w01[s] * vA1 +
                                w10[s] * vB0 + w11[s] * vB1);
            }
        }
    } else {
        // Fallback: direct global gathers (round-1 proven path)
        int offA[Sc], offB[Sc];
#pragma unroll
        for (int s = 0; s < Sc; ++s) {
            offA[s] = y09[s] * Wc + xb9[s];
            offB[s] = y19[s] * Wc + xb9[s];
        }
        for (int c = 0; c < GCc; ++c) {
            const float lv = Lb[(size_t)c * HWc];
            const float* Rc = Rb + (size_t)c * HWc;
#pragma unroll
            for (int s = 0; s < Sc; ++s) {
                const float vA0 = Rc[offA[s]];
                const float vA1 = Rc[offA[s] + 1];
                const float vB0 = Rc[offB[s]];
                const float vB1 = Rc[offB[s] + 1];
                acc[s] += lv * (w00[s] * vA0 + w01[s] * vA1 +
                                w10[s] * vB0 + w11[s] * vB1);
            }
        }
    }

    const float inv = 1.0f / (float)GCc;
    float* ob = out + ((size_t)b * Gc + g) * Sc * HWc + pix;
#pragma unroll
    for (int s = 0; s < Sc; ++s) ob[(size_t)s * HWc] = acc[s] * inv;
}

extern "C" void kernel_launch(void* const* d_in, const int* in_sizes, int n_in,
                              void* d_out, int out_size, void* d_ws, size_t ws_size,
                              hipStream_t stream) {
    const float* left  = (const float*)d_in[0];
    const float* right = (const float*)d_in[1];
    const float* flow  = (const float*)d_in[2];
    const float* extra = (const float*)d_in[3];
    float* out = (float*)d_out;

    const int nblocks = Bc * Gc * H2c * WTc;  // 2*4*40*5 = 1600
    aoc_corr_kernel<<<nblocks, 64, 0, stream>>>(left, right, flow, extra, out);
}

// Round 3
// 64.458 us; speedup vs baseline: 2.1378x; 1.2615x over previous
//
#include <hip/hip_runtime.h>

// Problem constants (fixed by the reference setup)
#define Bc   2
#define Cc   256
#define Hc   80
#define Wc   160
#define Gc   4
#define Sc   9
#define GCc  64              // channels per group
#define HWc  (Hc * Wc)
#define H2c  (Hc / 2)        // 40 row-pair tiles
#define WTc  (Wc / 32)       // 5 col tiles of 32
#define CPW  32              // channels per wave (2 waves split a group)

// LDS staging region budget (per wave, double-buffered)
#define RROWS   24
#define RCOLS   64
#define RSTRIDE 65           // +1 pad: bank = (y + x) mod 32

typedef const __attribute__((address_space(1))) unsigned int* gas_ptr;
typedef __attribute__((address_space(3))) unsigned int* las_ptr;

// Block = 128 threads = 2 waves, both covering the same (b, g, 2x32 pixel
// tile); wave w handles channels [w*32, w*32+32) and they reduce at the end.
// Per wave: double-buffered LDS staging of the sample footprint with a
// COUNTED vmcnt (stage of channel c+1 stays in flight under the LDS reads +
// FMAs of channel c) — round 2 was serialized on a per-channel vmcnt(0)
// drain (~560 cyc/iter at only 6 waves/CU).
__global__ __launch_bounds__(128)
void aoc_corr_kernel(const float* __restrict__ left,
                     const float* __restrict__ right,
                     const float* __restrict__ flow,
                     const float* __restrict__ extra,
                     float* __restrict__ out)
{
    // [wave][buf][region]; reduce buffer aliased onto this after compute.
    __shared__ float tile[2][2][RROWS * RSTRIDE];

    int bid = blockIdx.x;
    int wt = bid % WTc; bid /= WTc;
    int h2 = bid % H2c; bid /= H2c;
    int g  = bid % Gc;  bid /= Gc;
    int b  = bid;

    const int tid  = threadIdx.x;
    const int wid  = tid >> 6;
    const int lane = tid & 63;
    const int r    = lane >> 5;
    const int col  = lane & 31;
    const int h    = h2 * 2 + r;
    const int w    = wt * 32 + col;
    const int pix  = h * Wc + w;

    const float* flowb = flow + (size_t)b * 2 * HWc;
    const float bx = (float)w + flowb[pix];
    const float by = (float)h + flowb[HWc + pix];

    int   xb9[Sc], y09[Sc], y19[Sc];
    float w00[Sc], w01[Sc], w10[Sc], w11[Sc];
    int minX = 1 << 30, maxX = -(1 << 30), minY = 1 << 30, maxY = -(1 << 30);

    const float* exb = extra + (size_t)b * (2 * Sc) * HWc + pix;
#pragma unroll
    for (int s = 0; s < Sc; ++s) {
        const float ex = exb[(size_t)(2 * s) * HWc];
        const float ey = exb[(size_t)(2 * s + 1) * HWc];
        const float x = bx + (float)(s - 4) + ex;   // window: x offset s-4, y 0
        const float y = by + ey;

        const float x0f = floorf(x);
        const float y0f = floorf(y);
        const float fx = x - x0f;
        const float fy = y - y0f;
        const int x0 = (int)x0f;
        const int y0 = (int)y0f;
        const int y1 = y0 + 1;

        const int xb = min(max(x0, 0), Wc - 2);
        const float cA = (x0 == xb) ? (1.0f - fx) : ((x0 == -1)     ? fx          : 0.0f);
        const float cB = (x0 == xb) ? fx          : ((x0 == Wc - 1) ? (1.0f - fx) : 0.0f);
        const float r0 = (y0 >= 0 && y0 < Hc) ? (1.0f - fy) : 0.0f;
        const float r1 = (y1 >= 0 && y1 < Hc) ? fy          : 0.0f;
        const int yc0 = min(max(y0, 0), Hc - 1);
        const int yc1 = min(max(y1, 0), Hc - 1);

        w00[s] = cA * r0;  w01[s] = cB * r0;
        w10[s] = cA * r1;  w11[s] = cB * r1;
        xb9[s] = xb;  y09[s] = yc0;  y19[s] = yc1;

        minX = min(minX, xb);
        maxX = max(maxX, xb);
        minY = min(minY, min(yc0, yc1));
        maxY = max(maxY, max(yc0, yc1));
    }

    // Wave-wide min/max of the (clamped) footprint — identical for both waves.
#pragma unroll
    for (int k = 1; k < 64; k <<= 1) {
        minX = min(minX, __shfl_xor(minX, k));
        maxX = max(maxX, __shfl_xor(maxX, k));
        minY = min(minY, __shfl_xor(minY, k));
        maxY = max(maxY, __shfl_xor(maxY, k));
    }
    const int nRows = maxY - minY + 1;
    const int nCols = maxX + 2 - minX;

    const float* Rb = right + ((size_t)b * Cc + (size_t)(g * GCc + wid * CPW)) * HWc;
    const float* Lb = left  + ((size_t)b * Cc + (size_t)(g * GCc + wid * CPW)) * HWc + pix;

    float acc[Sc];
#pragma unroll
    for (int s = 0; s < Sc; ++s) acc[s] = 0.0f;

    if (nRows <= RROWS && nCols <= RCOLS) {
        int relA[Sc], relB[Sc];
#pragma unroll
        for (int s = 0; s < Sc; ++s) {
            relA[s] = (y09[s] - minY) * RSTRIDE + (xb9[s] - minX);
            relB[s] = (y19[s] - minY) * RSTRIDE + (xb9[s] - minX);
        }
        // Lane -> staged absolute column (clamped; clamped dups never read)
        const int colAbs = minX + min(lane, (Wc - 1) - minX);

        // Always stage exactly RROWS rows (row index clamped in-plane) so the
        // outstanding-load count is a compile-time constant for s_waitcnt.
        auto stage = [&](int bufi, int c) {
            const float* Rc = Rb + (size_t)c * HWc;
#pragma unroll
            for (int rr = 0; rr < RROWS; ++rr) {
                const int ro = min(minY + rr, Hc - 1);
                __builtin_amdgcn_global_load_lds(
                    (gas_ptr)(Rc + ro * Wc + colAbs),
                    (las_ptr)&tile[wid][bufi][rr * RSTRIDE], 4, 0, 0);
            }
        };

        stage(0, 0);
        float lv = Lb[0];
        for (int c = 0; c < CPW; ++c) {
            const int cur = c & 1;
            // WAR: previous iter's ds_reads retired before overwriting buf
            asm volatile("s_waitcnt lgkmcnt(0)" ::: "memory");
            float lvn = 0.0f;
            if (c + 1 < CPW) {
                stage(cur ^ 1, c + 1);
                // stage(c) complete; stage(c+1)'s 24 loads stay in flight
                asm volatile("s_waitcnt vmcnt(24)" ::: "memory");
                lvn = Lb[(size_t)(c + 1) * HWc];
            } else {
                asm volatile("s_waitcnt vmcnt(0)" ::: "memory");
            }
            const float* tl = tile[wid][cur];
#pragma unroll
            for (int s = 0; s < Sc; ++s) {
                const float vA0 = tl[relA[s]];
                const float vA1 = tl[relA[s] + 1];
                const float vB0 = tl[relB[s]];
                const float vB1 = tl[relB[s] + 1];
                acc[s] += lv * (w00[s] * vA0 + w01[s] * vA1 +
                                w10[s] * vB0 + w11[s] * vB1);
            }
            lv = lvn;
        }
    } else {
        // Fallback: direct global gathers (proven path; footprint outliers)
        int offA[Sc], offB[Sc];
#pragma unroll
        for (int s = 0; s < Sc; ++s) {
            offA[s] = y09[s] * Wc + xb9[s];
            offB[s] = y19[s] * Wc + xb9[s];
        }
        for (int c = 0; c < CPW; ++c) {
            const float lv = Lb[(size_t)c * HWc];
            const float* Rc = Rb + (size_t)c * HWc;
#pragma unroll
            for (int s = 0; s < Sc; ++s) {
                const float vA0 = Rc[offA[s]];
                const float vA1 = Rc[offA[s] + 1];
                const float vB0 = Rc[offB[s]];
                const float vB1 = Rc[offB[s] + 1];
                acc[s] += lv * (w00[s] * vA0 + w01[s] * vA1 +
                                w10[s] * vB0 + w11[s] * vB1);
            }
        }
    }

    // Cross-wave reduction. Reduce buffer aliases the (now dead) tile memory;
    // barrier first so no lane still reads its tile.
    float* red = &tile[0][0][0];   // Sc*64 floats
    __syncthreads();
    if (wid == 1) {
#pragma unroll
        for (int s = 0; s < Sc; ++s) red[s * 64 + lane] = acc[s];
    }
    __syncthreads();
    if (wid == 0) {
        const float inv = 1.0f / (float)GCc;
        float* ob = out + ((size_t)b * Gc + g) * Sc * HWc + pix;
#pragma unroll
        for (int s = 0; s < Sc; ++s)
            ob[(size_t)s * HWc] = (acc[s] + red[s * 64 + lane]) * inv;
    }
}

extern "C" void kernel_launch(void* const* d_in, const int* in_sizes, int n_in,
                              void* d_out, int out_size, void* d_ws, size_t ws_size,
                              hipStream_t stream) {
    const float* left  = (const float*)d_in[0];
    const float* right = (const float*)d_in[1];
    const float* flow  = (const float*)d_in[2];
    const float* extra = (const float*)d_in[3];
    float* out = (float*)d_out;

    const int nblocks = Bc * Gc * H2c * WTc;  // 2*4*40*5 = 1600
    aoc_corr_kernel<<<nblocks, 128, 0, stream>>>(left, right, flow, extra, out);
}